// Round 1
// baseline (658.313 us; speedup 1.0000x reference)
//
#include <hip/hip_runtime.h>

// Problem constants (hard-coded per reference)
#define B_SZ 512
#define I_SZ 7
#define D_SZ 512
#define J_SZ 64
#define E_SZ 128
#define N_SZ (J_SZ * E_SZ)   // 8192
#define ITERS 10

// ---------------------------------------------------------------------------
// Kernel 1: vote GEMM (fp32, vector ALU — no fp32 MFMA on CDNA4)
// fW[b,i,j,e] = sum_d f[b,i,d] * W[i,d,j,e]
// Per i: C[512, 8192] = A[512,512] (rows strided by I*D) * B[512, 8192]
// 64x64 tile, BK=16, 256 threads, 4x4 micro-tile.
// ---------------------------------------------------------------------------
__global__ __launch_bounds__(256) void vote_gemm(
    const float* __restrict__ f,   // [B, I, D]
    const float* __restrict__ W,   // [I, D, J*E]
    float* __restrict__ fW)        // [B, I, J*E]
{
    const int i   = blockIdx.z;
    const int m0  = blockIdx.y * 64;   // b tile
    const int n0  = blockIdx.x * 64;   // je tile
    const int tid = threadIdx.x;

    // stride 68 floats: 16B-aligned rows, conflict-free b128 reads
    __shared__ float As[16][68];   // transposed A tile: As[k][m]
    __shared__ float Bs[16][68];

    const int a_m = tid >> 2;          // 0..63
    const int a_k = (tid & 3) << 2;    // 0,4,8,12
    const int b_k = tid >> 4;          // 0..15
    const int b_n = (tid & 15) << 2;   // 0..60
    const int tm  = (tid >> 4) << 2;   // micro-tile row base
    const int tn  = (tid & 15) << 2;   // micro-tile col base

    float acc[4][4] = {};

    const float* fA = f + (size_t)(m0 + a_m) * (I_SZ * D_SZ) + (size_t)i * D_SZ + a_k;
    const float* WB = W + (size_t)i * D_SZ * N_SZ + (size_t)b_k * N_SZ + n0 + b_n;

    for (int k0 = 0; k0 < D_SZ; k0 += 16) {
        // issue global loads before the barrier to overlap latency
        float4 av = *(const float4*)(fA + k0);
        float4 bv = *(const float4*)(WB + (size_t)k0 * N_SZ);
        __syncthreads();   // protect previous tile's LDS reads
        As[a_k + 0][a_m] = av.x;
        As[a_k + 1][a_m] = av.y;
        As[a_k + 2][a_m] = av.z;
        As[a_k + 3][a_m] = av.w;
        *(float4*)&Bs[b_k][b_n] = bv;
        __syncthreads();
#pragma unroll
        for (int k = 0; k < 16; ++k) {
            float4 a4 = *(const float4*)&As[k][tm];
            float4 b4 = *(const float4*)&Bs[k][tn];
            const float aa[4] = {a4.x, a4.y, a4.z, a4.w};
            const float bb[4] = {b4.x, b4.y, b4.z, b4.w};
#pragma unroll
            for (int mi = 0; mi < 4; ++mi)
#pragma unroll
                for (int ni = 0; ni < 4; ++ni)
                    acc[mi][ni] = fmaf(aa[mi], bb[ni], acc[mi][ni]);
        }
    }

    // write C: fW[(b*I + i)*N + n]
#pragma unroll
    for (int mi = 0; mi < 4; ++mi) {
        float4 o = make_float4(acc[mi][0], acc[mi][1], acc[mi][2], acc[mi][3]);
        float* C = fW + ((size_t)(m0 + tm + mi) * I_SZ + i) * N_SZ + n0 + tn;
        *(float4*)C = o;
    }
}

// ---------------------------------------------------------------------------
// Kernel 2: routing iterations — one block per b, everything local.
// c[64][128] lives in LDS across all 10 iterations.
// Per (iter, i): stage fW[b,i] (32KB) once -> logits -> softmax -> c accum.
// Thread mapping: j = tid&63 (lane), q = tid>>6 (wave) owns e in [q*32, q*32+32).
// LDS row stride 132: b128-aligned, minimal bank-group conflicts for this map.
// ---------------------------------------------------------------------------
__global__ __launch_bounds__(256) void routing_kernel(
    const float* __restrict__ fW,  // [B, I, J*E]
    const float* __restrict__ p,   // [B, I]
    float* __restrict__ c_out,     // [B, J, E]
    float* __restrict__ r_out)     // [B, I, J]
{
    const int b   = blockIdx.x;
    const int tid = threadIdx.x;
    const int j   = tid & 63;
    const int q   = tid >> 6;

    __shared__ float c_sh[64][132];
    __shared__ float fWs[64][132];
    __shared__ float part[4][64];
    __shared__ float r_sh[64];
    __shared__ float p_sh[8];

    if (tid < I_SZ) p_sh[tid] = p[(size_t)b * I_SZ + tid];

    // c0 = ones
    {
        float4 one4 = make_float4(1.f, 1.f, 1.f, 1.f);
#pragma unroll
        for (int u = 0; u < 8; ++u)
            *(float4*)&c_sh[j][q * 32 + 4 * u] = one4;
    }

    const float* fWb = fW + (size_t)b * I_SZ * N_SZ;
    float4 acc[8];

    for (int it = 0; it < ITERS; ++it) {
        const bool last = (it == ITERS - 1);
#pragma unroll
        for (int u = 0; u < 8; ++u) acc[u] = make_float4(0.f, 0.f, 0.f, 0.f);

        for (int i = 0; i < I_SZ; ++i) {
            __syncthreads();  // (a) fWs reuse fence + c_sh update visibility
            // stage fW[b,i] -> LDS (coalesced float4, 8 per thread)
            const float* src = fWb + (size_t)i * N_SZ;
#pragma unroll
            for (int v = 0; v < 8; ++v) {
                int idx = (v * 256 + tid) * 4;
                float4 d = *(const float4*)(src + idx);
                *(float4*)&fWs[idx >> 7][idx & 127] = d;
            }
            __syncthreads();  // (b) staging visible

            // partial logits: dot(fW[b,i,j,:], c[j,:]) over this thread's e-chunk
            float pt = 0.f;
#pragma unroll
            for (int u = 0; u < 8; ++u) {
                float4 a = *(const float4*)&fWs[j][q * 32 + 4 * u];
                float4 c = *(const float4*)&c_sh[j][q * 32 + 4 * u];
                pt += a.x * c.x + a.y * c.y + a.z * c.z + a.w * c.w;
            }
            part[q][j] = pt;
            __syncthreads();  // (c) partials visible

            // softmax over j (64 values) on wave 0
            if (tid < 64) {
                float lg = part[0][j] + part[1][j] + part[2][j] + part[3][j];
                float mx = lg;
#pragma unroll
                for (int off = 32; off > 0; off >>= 1)
                    mx = fmaxf(mx, __shfl_xor(mx, off));
                float ex = __expf(lg - mx);
                float sm = ex;
#pragma unroll
                for (int off = 32; off > 0; off >>= 1)
                    sm += __shfl_xor(sm, off);
                float r = ex / sm;
                r_sh[j] = r;
                if (last)
                    r_out[(size_t)b * (I_SZ * J_SZ) + (size_t)i * J_SZ + j] = r;
            }
            __syncthreads();  // (d) r_sh visible

            // c_next accumulation: acc[j][e] += p[i]*r[i][j]*fW[b,i,j,e]
            float coef = p_sh[i] * r_sh[j];
#pragma unroll
            for (int u = 0; u < 8; ++u) {
                float4 a = *(const float4*)&fWs[j][q * 32 + 4 * u];
                acc[u].x = fmaf(coef, a.x, acc[u].x);
                acc[u].y = fmaf(coef, a.y, acc[u].y);
                acc[u].z = fmaf(coef, a.z, acc[u].z);
                acc[u].w = fmaf(coef, a.w, acc[u].w);
            }
        }

        // commit c_next (no race: last c_sh read was fenced at (c) of i=6,
        // and each thread writes only its own (j, e-chunk) segment)
        if (last) {
            float* dst = c_out + (size_t)b * N_SZ + (size_t)j * E_SZ + q * 32;
#pragma unroll
            for (int u = 0; u < 8; ++u)
                *(float4*)(dst + 4 * u) = acc[u];
        } else {
#pragma unroll
            for (int u = 0; u < 8; ++u)
                *(float4*)&c_sh[j][q * 32 + 4 * u] = acc[u];
        }
    }
}

extern "C" void kernel_launch(void* const* d_in, const int* in_sizes, int n_in,
                              void* d_out, int out_size, void* d_ws, size_t ws_size,
                              hipStream_t stream) {
    const float* f = (const float*)d_in[0];   // [512,7,512]
    const float* p = (const float*)d_in[1];   // [512,7]
    const float* W = (const float*)d_in[2];   // [7,512,64,128]
    float* out = (float*)d_out;               // c (512*64*128) then r (512*7*64)
    float* fW  = (float*)d_ws;                // 29,360,128 floats = 117.4 MB

    vote_gemm<<<dim3(N_SZ / 64, B_SZ / 64, I_SZ), 256, 0, stream>>>(f, W, fW);
    routing_kernel<<<B_SZ, 256, 0, stream>>>(fW, p, out, out + (size_t)B_SZ * N_SZ);
}

// Round 2
// 548.700 us; speedup vs baseline: 1.1998x; 1.1998x over previous
//
#include <hip/hip_runtime.h>

#define B_SZ 512
#define I_SZ 7
#define D_SZ 512
#define J_SZ 64
#define E_SZ 128
#define N_SZ (J_SZ * E_SZ)   // 8192
#define ITERS 10

// ---------------------------------------------------------------------------
// Kernel 1: vote GEMM (fp32, vector ALU).
// fW[b,i,j,e] = sum_d f[b,i,d] * W[i,d,j,e]
// 128x128 tile, BK=16, 256 threads, 8x8 micro-tile, pipelined global loads.
// ---------------------------------------------------------------------------
__global__ __launch_bounds__(256) void vote_gemm(
    const float* __restrict__ f,   // [B, I, D]
    const float* __restrict__ W,   // [I, D, J*E]
    float* __restrict__ fW)        // [B, I, J*E]
{
    const int i   = blockIdx.z;
    const int m0  = blockIdx.y * 128;  // b tile
    const int n0  = blockIdx.x * 128;  // je tile
    const int tid = threadIdx.x;

    // stride 132: 16B-aligned rows; reads are broadcast (As) / 2-way (Bs) = free
    __shared__ float As[16][132];   // transposed A: As[k][m]
    __shared__ float Bs[16][132];   // Bs[k][n]

    // A staging: 2 float4 per thread, one row-pair of d's
    const int a_m = tid >> 1;          // 0..127 (b row)
    const int a_k = (tid & 1) * 8;     // 0 or 8
    // B staging: 2 float4 per thread
    const int b_k = tid >> 5;          // 0..7 (+8 on second pass)
    const int b_n = (tid & 31) * 4;    // 0..124

    const int ty = tid >> 4;           // 0..15 -> m micro row
    const int tx = tid & 15;           // 0..15 -> n micro col

    float acc[8][8] = {};

    const float* fA = f + (size_t)(m0 + a_m) * (I_SZ * D_SZ) + (size_t)i * D_SZ + a_k;
    const float* WB = W + (size_t)i * D_SZ * N_SZ + n0 + b_n;

    float4 av0 = *(const float4*)(fA);
    float4 av1 = *(const float4*)(fA + 4);
    float4 bv0 = *(const float4*)(WB + (size_t)b_k * N_SZ);
    float4 bv1 = *(const float4*)(WB + (size_t)(b_k + 8) * N_SZ);

    for (int k0 = 0; k0 < D_SZ; k0 += 16) {
        __syncthreads();   // previous tile's LDS reads done
        As[a_k + 0][a_m] = av0.x;
        As[a_k + 1][a_m] = av0.y;
        As[a_k + 2][a_m] = av0.z;
        As[a_k + 3][a_m] = av0.w;
        As[a_k + 4][a_m] = av1.x;
        As[a_k + 5][a_m] = av1.y;
        As[a_k + 6][a_m] = av1.z;
        As[a_k + 7][a_m] = av1.w;
        *(float4*)&Bs[b_k][b_n]     = bv0;
        *(float4*)&Bs[b_k + 8][b_n] = bv1;
        __syncthreads();

        if (k0 + 16 < D_SZ) {  // issue next tile's loads; latency hides under FMAs
            av0 = *(const float4*)(fA + k0 + 16);
            av1 = *(const float4*)(fA + k0 + 20);
            bv0 = *(const float4*)(WB + (size_t)(k0 + 16 + b_k) * N_SZ);
            bv1 = *(const float4*)(WB + (size_t)(k0 + 24 + b_k) * N_SZ);
        }

#pragma unroll
        for (int k = 0; k < 16; ++k) {
            float4 a0 = *(const float4*)&As[k][ty * 8];
            float4 a1 = *(const float4*)&As[k][ty * 8 + 4];
            float4 b0 = *(const float4*)&Bs[k][tx * 8];
            float4 b1 = *(const float4*)&Bs[k][tx * 8 + 4];
            const float aa[8] = {a0.x, a0.y, a0.z, a0.w, a1.x, a1.y, a1.z, a1.w};
            const float bb[8] = {b0.x, b0.y, b0.z, b0.w, b1.x, b1.y, b1.z, b1.w};
#pragma unroll
            for (int mi = 0; mi < 8; ++mi)
#pragma unroll
                for (int ni = 0; ni < 8; ++ni)
                    acc[mi][ni] = fmaf(aa[mi], bb[ni], acc[mi][ni]);
        }
    }

    // write C: fW[(b*I + i)*N + n]
#pragma unroll
    for (int mi = 0; mi < 8; ++mi) {
        float* C = fW + ((size_t)(m0 + ty * 8 + mi) * I_SZ + i) * N_SZ + n0 + tx * 8;
        *(float4*)(C)     = make_float4(acc[mi][0], acc[mi][1], acc[mi][2], acc[mi][3]);
        *(float4*)(C + 4) = make_float4(acc[mi][4], acc[mi][5], acc[mi][6], acc[mi][7]);
    }
}

// ---------------------------------------------------------------------------
// Kernel 2: routing, fully register-resident.
// 1024 threads per block, one block per b.
// Thread (j = tid>>4, sub = tid&15) owns fW[b, :, j, sub*8 .. sub*8+8) in
// registers (56 VGPRs) and the matching c/acc slice (8 VGPRs each).
// Logits: in-register dot + 16-lane xor-shuffle reduce (the 16 threads of a
// j are contiguous lanes within one wave). Softmax over j: LDS 7x64 table,
// waves 0..6 each handle one i. 2 barriers per iteration.
// ---------------------------------------------------------------------------
__global__ __launch_bounds__(1024) void routing_kernel(
    const float* __restrict__ fW,  // [B, I, J*E]
    const float* __restrict__ p,   // [B, I]
    float* __restrict__ c_out,     // [B, J, E]
    float* __restrict__ r_out)     // [B, I, J]
{
    const int b   = blockIdx.x;
    const int tid = threadIdx.x;
    const int j   = tid >> 4;      // 0..63
    const int sub = tid & 15;      // e-chunk: [sub*8, sub*8+8)

    __shared__ float logit_sh[I_SZ][64];
    __shared__ float r_sh[I_SZ][64];

    // load this thread's fW slice into registers: 7 i x 8 e = 56 floats
    float4 fw[I_SZ][2];
    const float* base = fW + (size_t)b * I_SZ * N_SZ + j * E_SZ + sub * 8;
#pragma unroll
    for (int i = 0; i < I_SZ; ++i) {
        fw[i][0] = *(const float4*)(base + (size_t)i * N_SZ);
        fw[i][1] = *(const float4*)(base + (size_t)i * N_SZ + 4);
    }
    float pv[I_SZ];
#pragma unroll
    for (int i = 0; i < I_SZ; ++i) pv[i] = p[(size_t)b * I_SZ + i];

    float4 c0 = make_float4(1.f, 1.f, 1.f, 1.f);
    float4 c1 = make_float4(1.f, 1.f, 1.f, 1.f);

    for (int it = 0; it < ITERS; ++it) {
        const bool last = (it == ITERS - 1);

        // logits: lg[i] = dot(fW[b,i,j,:], c[j,:]) reduced over the 16 threads of j
#pragma unroll
        for (int i = 0; i < I_SZ; ++i) {
            float4 a0 = fw[i][0], a1 = fw[i][1];
            float pt = a0.x * c0.x + a0.y * c0.y + a0.z * c0.z + a0.w * c0.w
                     + a1.x * c1.x + a1.y * c1.y + a1.z * c1.z + a1.w * c1.w;
#pragma unroll
            for (int off = 8; off > 0; off >>= 1)
                pt += __shfl_xor(pt, off);
            if (sub == 0) logit_sh[i][j] = pt;
        }
        __syncthreads();

        // softmax over j: wave i handles row i (threads 64*i .. 64*i+63)
        if (tid < I_SZ * 64) {
            const int i  = tid >> 6;
            const int jj = tid & 63;
            float lg = logit_sh[i][jj];
            float mx = lg;
#pragma unroll
            for (int off = 32; off > 0; off >>= 1)
                mx = fmaxf(mx, __shfl_xor(mx, off));
            float ex = __expf(lg - mx);
            float sm = ex;
#pragma unroll
            for (int off = 32; off > 0; off >>= 1)
                sm += __shfl_xor(sm, off);
            float r = ex / sm;
            r_sh[i][jj] = r;
            if (last)
                r_out[(size_t)b * (I_SZ * J_SZ) + (size_t)i * J_SZ + jj] = r;
        }
        __syncthreads();

        // c_next[j,e] = sum_i p[i] * r[i][j] * fW[i,j,e]  (all in registers)
        float4 a0 = make_float4(0.f, 0.f, 0.f, 0.f);
        float4 a1 = make_float4(0.f, 0.f, 0.f, 0.f);
#pragma unroll
        for (int i = 0; i < I_SZ; ++i) {
            float coef = pv[i] * r_sh[i][j];
            float4 w0 = fw[i][0], w1 = fw[i][1];
            a0.x = fmaf(coef, w0.x, a0.x);
            a0.y = fmaf(coef, w0.y, a0.y);
            a0.z = fmaf(coef, w0.z, a0.z);
            a0.w = fmaf(coef, w0.w, a0.w);
            a1.x = fmaf(coef, w1.x, a1.x);
            a1.y = fmaf(coef, w1.y, a1.y);
            a1.z = fmaf(coef, w1.z, a1.z);
            a1.w = fmaf(coef, w1.w, a1.w);
        }
        c0 = a0;
        c1 = a1;
    }

    float* dst = c_out + (size_t)b * N_SZ + j * E_SZ + sub * 8;
    *(float4*)(dst)     = c0;
    *(float4*)(dst + 4) = c1;
}

extern "C" void kernel_launch(void* const* d_in, const int* in_sizes, int n_in,
                              void* d_out, int out_size, void* d_ws, size_t ws_size,
                              hipStream_t stream) {
    const float* f = (const float*)d_in[0];   // [512,7,512]
    const float* p = (const float*)d_in[1];   // [512,7]
    const float* W = (const float*)d_in[2];   // [7,512,64,128]
    float* out = (float*)d_out;               // c (512*64*128) then r (512*7*64)
    float* fW  = (float*)d_ws;                // 117.4 MB scratch

    vote_gemm<<<dim3(N_SZ / 128, B_SZ / 128, I_SZ), 256, 0, stream>>>(f, W, fW);
    routing_kernel<<<B_SZ, 1024, 0, stream>>>(fW, p, out, out + (size_t)B_SZ * N_SZ);
}

// Round 3
// 542.072 us; speedup vs baseline: 1.2144x; 1.0122x over previous
//
#include <hip/hip_runtime.h>

#define B_SZ 512
#define I_SZ 7
#define D_SZ 512
#define J_SZ 64
#define E_SZ 128
#define N_SZ 8192
#define ITERS 10

// ---------------------------------------------------------------------------
// Kernel 1: vote GEMM (fp32 vector ALU).
// fW[b,i,j,e] = sum_d f[b,i,d] * W[i,d,j,e]
// 128x128 tile, BK=32, 256 threads, 8x8 micro-tile with 4+4 split columns/rows
// (conflict-free b128 LDS reads: 16 consecutive float4 per quarter-wave).
// Register prefetch of the next tile; 2 barriers per BK=32 (2048 FMA between).
// ---------------------------------------------------------------------------
__global__ __launch_bounds__(256, 3) void vote_gemm(
    const float* __restrict__ f,   // [B, I, D]
    const float* __restrict__ W,   // [I, D, J*E]
    float* __restrict__ fW)        // [B, I, J*E]
{
    const int i   = blockIdx.z;
    const int m0  = blockIdx.y * 128;  // b tile
    const int n0  = blockIdx.x * 128;  // je tile
    const int tid = threadIdx.x;

    __shared__ float As[32][132];   // transposed A: As[k][m]
    __shared__ float Bs[32][132];   // Bs[k][n]

    // A staging: 16 floats (4 float4) per thread
    const int a_m = tid >> 1;           // 0..127 (b row)
    const int a_k = (tid & 1) * 16;     // 0 or 16
    // B staging: 4 float4 per thread
    const int b_k = tid >> 5;           // 0..7 (+8s)
    const int b_n = (tid & 31) * 4;     // 0..124

    const int ty = tid >> 4;            // 0..15
    const int tx = tid & 15;            // 0..15
    // rows: ty*4+mi and 64+ty*4+mi ; cols: tx*4+ni and 64+tx*4+ni

    float acc[8][8] = {};

    const float* fA = f + (size_t)(m0 + a_m) * (I_SZ * D_SZ) + (size_t)i * D_SZ + a_k;
    const float* WB = W + (size_t)i * D_SZ * N_SZ + n0 + b_n;

    float4 av[4], bv[4];
#pragma unroll
    for (int u = 0; u < 4; ++u) av[u] = *(const float4*)(fA + 4 * u);
#pragma unroll
    for (int s = 0; s < 4; ++s) bv[s] = *(const float4*)(WB + (size_t)(b_k + 8 * s) * N_SZ);

    for (int k0 = 0; k0 < D_SZ; k0 += 32) {
        __syncthreads();   // previous tile's LDS reads complete
#pragma unroll
        for (int u = 0; u < 4; ++u) {
            As[a_k + 4 * u + 0][a_m] = av[u].x;
            As[a_k + 4 * u + 1][a_m] = av[u].y;
            As[a_k + 4 * u + 2][a_m] = av[u].z;
            As[a_k + 4 * u + 3][a_m] = av[u].w;
        }
#pragma unroll
        for (int s = 0; s < 4; ++s)
            *(float4*)&Bs[b_k + 8 * s][b_n] = bv[s];
        __syncthreads();

        if (k0 + 32 < D_SZ) {   // prefetch next tile; hidden under 2048 FMAs
#pragma unroll
            for (int u = 0; u < 4; ++u) av[u] = *(const float4*)(fA + k0 + 32 + 4 * u);
#pragma unroll
            for (int s = 0; s < 4; ++s) bv[s] = *(const float4*)(WB + (size_t)(k0 + 32 + b_k + 8 * s) * N_SZ);
        }

#pragma unroll 16
        for (int k = 0; k < 32; ++k) {
            float4 a0 = *(const float4*)&As[k][ty * 4];
            float4 a1 = *(const float4*)&As[k][64 + ty * 4];
            float4 b0 = *(const float4*)&Bs[k][tx * 4];
            float4 b1 = *(const float4*)&Bs[k][64 + tx * 4];
            const float aa[8] = {a0.x, a0.y, a0.z, a0.w, a1.x, a1.y, a1.z, a1.w};
            const float bb[8] = {b0.x, b0.y, b0.z, b0.w, b1.x, b1.y, b1.z, b1.w};
#pragma unroll
            for (int mi = 0; mi < 8; ++mi)
#pragma unroll
                for (int ni = 0; ni < 8; ++ni)
                    acc[mi][ni] = fmaf(aa[mi], bb[ni], acc[mi][ni]);
        }
    }

    // write C: rows {ty*4+mi, 64+ty*4+mi}, cols {n0+tx*4, n0+64+tx*4}
#pragma unroll
    for (int mi = 0; mi < 8; ++mi) {
        const int row = (mi < 4) ? (ty * 4 + mi) : (64 + ty * 4 + mi - 4);
        float* C = fW + ((size_t)(m0 + row) * I_SZ + i) * N_SZ + n0;
        *(float4*)(C + tx * 4)      = make_float4(acc[mi][0], acc[mi][1], acc[mi][2], acc[mi][3]);
        *(float4*)(C + 64 + tx * 4) = make_float4(acc[mi][4], acc[mi][5], acc[mi][6], acc[mi][7]);
    }
}

// ---------------------------------------------------------------------------
// Kernel 2: routing via Gram matrices. One block (512 threads) per b.
// Thread (j = tid>>3, sub = tid&7) holds fW[b,:,j,sub*16..+16) in 112 VGPRs.
// Phase 1: G[j][i][i'] = <fW[i,j,:], fW[i',j,:]> and S[j][i] = sum_e fW
//          (register dot + 3-step shuffle over sub; one-time cost).
// Phase 2: 10 iterations on the 7x7 systems entirely in LDS:
//          l[i,j] = S (t=0) or sum_i' w[j,i']*G[j,i,i']; softmax over j
//          (wave-wide butterfly, wave ii owns i=ii); w = p*r. 1 barrier/iter,
//          double-buffered w. fW is never re-read.
// Phase 3: c[j,e] = sum_i w[j,i]*fw[i][e] from registers.
// ---------------------------------------------------------------------------
__global__ __launch_bounds__(512, 2) void routing_kernel(
    const float* __restrict__ fW,  // [B, I, J*E]
    const float* __restrict__ p,   // [B, I]
    float* __restrict__ c_out,     // [B, J, E]
    float* __restrict__ r_out)     // [B, I, J]
{
    const int b   = blockIdx.x;
    const int tid = threadIdx.x;
    const int j   = tid >> 3;      // 0..63
    const int sub = tid & 7;       // e-chunk [sub*16, sub*16+16)

    __shared__ float G_sh[64][49];     // odd stride -> 2-way max on strided reads
    __shared__ float s_sh[64][9];
    __shared__ float w_sh[2][64][9];
    __shared__ float p_sh[8];

    if (tid < I_SZ) p_sh[tid] = p[(size_t)b * I_SZ + tid];

    // register-resident fW slice: 7 x 16 e = 112 VGPRs
    float4 fw[I_SZ][4];
    const float* base = fW + (size_t)b * I_SZ * N_SZ + j * E_SZ + sub * 16;
#pragma unroll
    for (int i = 0; i < I_SZ; ++i)
#pragma unroll
        for (int u = 0; u < 4; ++u)
            fw[i][u] = *(const float4*)(base + (size_t)i * N_SZ + 4 * u);

    // ---- Phase 1: Gram + row-sums ----
#pragma unroll
    for (int i = 0; i < I_SZ; ++i) {
        float s = 0.f;
#pragma unroll
        for (int u = 0; u < 4; ++u)
            s += fw[i][u].x + fw[i][u].y + fw[i][u].z + fw[i][u].w;
        s += __shfl_xor(s, 1); s += __shfl_xor(s, 2); s += __shfl_xor(s, 4);
        if (sub == 0) s_sh[j][i] = s;
#pragma unroll
        for (int i2 = i; i2 < I_SZ; ++i2) {
            float g = 0.f;
#pragma unroll
            for (int u = 0; u < 4; ++u) {
                float4 a = fw[i][u], c = fw[i2][u];
                g += a.x * c.x + a.y * c.y + a.z * c.z + a.w * c.w;
            }
            g += __shfl_xor(g, 1); g += __shfl_xor(g, 2); g += __shfl_xor(g, 4);
            if (sub == 0) { G_sh[j][i * 7 + i2] = g; G_sh[j][i2 * 7 + i] = g; }
        }
    }
    __syncthreads();

    // ---- Phase 2: iterations on the 7x7 system ----
    for (int t = 0; t < ITERS; ++t) {
        if (tid < I_SZ * 64) {                 // waves 0..6 (wave-uniform branch)
            const int ii = tid >> 6;
            const int jj = tid & 63;
            float l;
            if (t == 0) {
                l = s_sh[jj][ii];              // c0 = ones
            } else {
                const int rb = t & 1;
                l = 0.f;
#pragma unroll
                for (int i2 = 0; i2 < I_SZ; ++i2)
                    l = fmaf(w_sh[rb][jj][i2], G_sh[jj][ii * 7 + i2], l);
            }
            // softmax over jj (wave-wide butterfly)
            float mx = l;
#pragma unroll
            for (int off = 32; off > 0; off >>= 1)
                mx = fmaxf(mx, __shfl_xor(mx, off));
            float ex = __expf(l - mx);
            float sm = ex;
#pragma unroll
            for (int off = 32; off > 0; off >>= 1)
                sm += __shfl_xor(sm, off);
            float r = ex / sm;
            if (t == ITERS - 1)
                r_out[(size_t)b * (I_SZ * J_SZ) + ii * 64 + jj] = r;
            w_sh[(t + 1) & 1][jj][ii] = p_sh[ii] * r;
        }
        __syncthreads();
    }

    // ---- Phase 3: reconstruct c from registers; final w in buffer 0 ----
    float4 acc[4] = {make_float4(0.f, 0.f, 0.f, 0.f), make_float4(0.f, 0.f, 0.f, 0.f),
                     make_float4(0.f, 0.f, 0.f, 0.f), make_float4(0.f, 0.f, 0.f, 0.f)};
#pragma unroll
    for (int i = 0; i < I_SZ; ++i) {
        float wv = w_sh[ITERS & 1][j][i];
#pragma unroll
        for (int u = 0; u < 4; ++u) {
            acc[u].x = fmaf(wv, fw[i][u].x, acc[u].x);
            acc[u].y = fmaf(wv, fw[i][u].y, acc[u].y);
            acc[u].z = fmaf(wv, fw[i][u].z, acc[u].z);
            acc[u].w = fmaf(wv, fw[i][u].w, acc[u].w);
        }
    }
    float* dst = c_out + (size_t)b * N_SZ + j * E_SZ + sub * 16;
#pragma unroll
    for (int u = 0; u < 4; ++u)
        *(float4*)(dst + 4 * u) = acc[u];
}

extern "C" void kernel_launch(void* const* d_in, const int* in_sizes, int n_in,
                              void* d_out, int out_size, void* d_ws, size_t ws_size,
                              hipStream_t stream) {
    const float* f = (const float*)d_in[0];   // [512,7,512]
    const float* p = (const float*)d_in[1];   // [512,7]
    const float* W = (const float*)d_in[2];   // [7,512,64,128]
    float* out = (float*)d_out;               // c (512*64*128) then r (512*7*64)
    float* fW  = (float*)d_ws;                // 117.4 MB scratch

    vote_gemm<<<dim3(N_SZ / 128, B_SZ / 128, I_SZ), 256, 0, stream>>>(f, W, fW);
    routing_kernel<<<B_SZ, 512, 0, stream>>>(fW, p, out, out + (size_t)B_SZ * N_SZ);
}

// Round 4
// 348.451 us; speedup vs baseline: 1.8893x; 1.5557x over previous
//
#include <hip/hip_runtime.h>
#include <hip/hip_bf16.h>

#define B_SZ 512
#define I_SZ 7
#define D_SZ 512
#define J_SZ 64
#define E_SZ 128
#define N_SZ 8192
#define ITERS 10

typedef __attribute__((ext_vector_type(8))) short bf16x8;
typedef __attribute__((ext_vector_type(4))) float f32x4;

#define AST 40   // LDS row stride in bf16 (32 k + 8 pad): bank-uniform b128
#define BST 40

// RNE split: x ~= hi + lo, both bf16; residual ~2^-18 |x|
__device__ inline void split_bf16(float x, short& h, short& l) {
    union { float f; unsigned u; } v; v.f = x;
    unsigned r = v.u + 0x7FFF + ((v.u >> 16) & 1);
    unsigned short hu = (unsigned short)(r >> 16);
    h = (short)hu;
    union { unsigned u; float f; } hb; hb.u = ((unsigned)hu) << 16;
    float res = x - hb.f;
    v.f = res;
    r = v.u + 0x7FFF + ((v.u >> 16) & 1);
    l = (short)(r >> 16);
}

// ---------------------------------------------------------------------------
// Kernel 1: vote GEMM via bf16 MFMA, 3-pass hi/lo split (fp32-grade accuracy).
// fW[b,i,j,e] = sum_d f[b,i,d]*W[i,d,j,e].  Per i: C[512,8192]=A[512,512]*B.
// 128x128 tile, BK=32, 256 threads (4 waves, each 64x64 = 4x4 MFMA tiles).
// acc += Ahi*Bhi + Ahi*Blo + Alo*Bhi  (lo*lo dropped: ~2^-18 rel).
// ---------------------------------------------------------------------------
__global__ __launch_bounds__(256) void vote_gemm_mfma(
    const float* __restrict__ f,   // [B, I, D]
    const float* __restrict__ W,   // [I, D, N]
    float* __restrict__ fW)        // [B, I, N]
{
    const int i  = blockIdx.z;
    const int m0 = blockIdx.y * 128;
    const int n0 = blockIdx.x * 128;
    const int th = threadIdx.x;

    __shared__ short As_hi[128 * AST], As_lo[128 * AST];  // [m][k]
    __shared__ short Bs_hi[128 * BST], Bs_lo[128 * BST];  // [n][k] (transposed)

    // A staging map: thread -> (row m, k-half)
    const int am  = th >> 1;          // 0..127
    const int akg = th & 1;           // k offset 16*akg
    // B staging map: thread -> (col n, k-half); loads run ALONG k, lanes span n
    const int bn  = th & 127;         // 0..127
    const int bkh = th >> 7;          // 0/1

    const float* fA = f + (size_t)(m0 + am) * (I_SZ * D_SZ) + (size_t)i * D_SZ + akg * 16;
    const float* WB = W + (size_t)i * D_SZ * N_SZ + n0 + bn;

    const int wave = th >> 6, lane = th & 63;
    const int wr = wave >> 1, wc = wave & 1;   // wave -> 64x64 quadrant
    const int lm = lane & 15, quad = lane >> 4;

    f32x4 acc[4][4];
#pragma unroll
    for (int a = 0; a < 4; ++a)
#pragma unroll
        for (int c = 0; c < 4; ++c)
            acc[a][c] = (f32x4){0.f, 0.f, 0.f, 0.f};

    for (int k0 = 0; k0 < D_SZ; k0 += 32) {
        // ---- global loads (fp32) ----
        float av[16];
        {
            const float* pa = fA + k0;
            float4 t0 = *(const float4*)(pa);
            float4 t1 = *(const float4*)(pa + 4);
            float4 t2 = *(const float4*)(pa + 8);
            float4 t3 = *(const float4*)(pa + 12);
            av[0]=t0.x; av[1]=t0.y; av[2]=t0.z; av[3]=t0.w;
            av[4]=t1.x; av[5]=t1.y; av[6]=t1.z; av[7]=t1.w;
            av[8]=t2.x; av[9]=t2.y; av[10]=t2.z; av[11]=t2.w;
            av[12]=t3.x; av[13]=t3.y; av[14]=t3.z; av[15]=t3.w;
        }
        float bv[16];
        {
            const float* pb = WB + (size_t)(k0 + bkh * 16) * N_SZ;
#pragma unroll
            for (int r = 0; r < 16; ++r) bv[r] = pb[(size_t)r * N_SZ];
        }

        // ---- convert to hi/lo bf16 vectors ----
        bf16x8 ah0, ah1, al0, al1, bh0, bh1, bl0, bl1;
#pragma unroll
        for (int u = 0; u < 8; ++u) {
            short h, l;
            split_bf16(av[u], h, l);      ah0[u] = h; al0[u] = l;
            split_bf16(av[u + 8], h, l);  ah1[u] = h; al1[u] = l;
            split_bf16(bv[u], h, l);      bh0[u] = h; bl0[u] = l;
            split_bf16(bv[u + 8], h, l);  bh1[u] = h; bl1[u] = l;
        }

        __syncthreads();   // previous tile's frag reads complete
        *(bf16x8*)&As_hi[am * AST + akg * 16]     = ah0;
        *(bf16x8*)&As_hi[am * AST + akg * 16 + 8] = ah1;
        *(bf16x8*)&As_lo[am * AST + akg * 16]     = al0;
        *(bf16x8*)&As_lo[am * AST + akg * 16 + 8] = al1;
        *(bf16x8*)&Bs_hi[bn * BST + bkh * 16]     = bh0;
        *(bf16x8*)&Bs_hi[bn * BST + bkh * 16 + 8] = bh1;
        *(bf16x8*)&Bs_lo[bn * BST + bkh * 16]     = bl0;
        *(bf16x8*)&Bs_lo[bn * BST + bkh * 16 + 8] = bl1;
        __syncthreads();   // staging visible

        // ---- fragment loads + MFMA ----
        bf16x8 Ah[4], Al[4], Bh[4], Bl[4];
#pragma unroll
        for (int t = 0; t < 4; ++t) {
            const int ar = (wr * 64 + t * 16 + lm) * AST + quad * 8;
            Ah[t] = *(const bf16x8*)&As_hi[ar];
            Al[t] = *(const bf16x8*)&As_lo[ar];
            const int br = (wc * 64 + t * 16 + lm) * BST + quad * 8;
            Bh[t] = *(const bf16x8*)&Bs_hi[br];
            Bl[t] = *(const bf16x8*)&Bs_lo[br];
        }
#pragma unroll
        for (int tm = 0; tm < 4; ++tm)
#pragma unroll
            for (int tn = 0; tn < 4; ++tn) {
                acc[tm][tn] = __builtin_amdgcn_mfma_f32_16x16x32_bf16(Ah[tm], Bh[tn], acc[tm][tn], 0, 0, 0);
                acc[tm][tn] = __builtin_amdgcn_mfma_f32_16x16x32_bf16(Ah[tm], Bl[tn], acc[tm][tn], 0, 0, 0);
                acc[tm][tn] = __builtin_amdgcn_mfma_f32_16x16x32_bf16(Al[tm], Bh[tn], acc[tm][tn], 0, 0, 0);
            }
    }

    // ---- write C: D layout col=lane&15, row=quad*4+reg ----
#pragma unroll
    for (int tm = 0; tm < 4; ++tm) {
        const int rowb = m0 + wr * 64 + tm * 16 + quad * 4;
#pragma unroll
        for (int tn = 0; tn < 4; ++tn) {
            const int col = n0 + wc * 64 + tn * 16 + lm;
#pragma unroll
            for (int r = 0; r < 4; ++r)
                fW[((size_t)(rowb + r) * I_SZ + i) * N_SZ + col] = acc[tm][tn][r];
        }
    }
}

// ---------------------------------------------------------------------------
// Kernel 2: routing via Gram matrices. 1024 threads per block, one block per b.
// Thread (j = tid>>4, sub = tid&15) holds fW[b,:,j,sub*8..+8) in 56 VGPRs
// (under the 128-reg cap for 1024-thread blocks -> no spill; 2 blocks/CU,
// all 512 blocks co-resident).
// Phase 1: G[j][i][i'] = <fW[i,j,:],fW[i',j,:]>, S[j][i] = sum_e (shuffle-reduced).
// Phase 2: 10 iterations on the 7x7 system in LDS; fW never re-read.
// Phase 3: c = sum_i w[j,i]*fw[i] from registers.
// ---------------------------------------------------------------------------
__global__ __launch_bounds__(1024) void routing_kernel(
    const float* __restrict__ fW,  // [B, I, N]
    const float* __restrict__ p,   // [B, I]
    float* __restrict__ c_out,     // [B, J, E]
    float* __restrict__ r_out)     // [B, I, J]
{
    const int b   = blockIdx.x;
    const int tid = threadIdx.x;
    const int j   = tid >> 4;      // 0..63
    const int sub = tid & 15;      // e-chunk [sub*8, sub*8+8)

    __shared__ float G_sh[64][49];
    __shared__ float s_sh[64][9];
    __shared__ float w_sh[2][64][9];
    __shared__ float p_sh[8];

    if (tid < I_SZ) p_sh[tid] = p[(size_t)b * I_SZ + tid];

    float4 fw[I_SZ][2];
    const float* base = fW + (size_t)b * I_SZ * N_SZ + j * E_SZ + sub * 8;
#pragma unroll
    for (int i = 0; i < I_SZ; ++i) {
        fw[i][0] = *(const float4*)(base + (size_t)i * N_SZ);
        fw[i][1] = *(const float4*)(base + (size_t)i * N_SZ + 4);
    }

    // ---- Phase 1: Gram + row sums (reduce over 16 sub-lanes) ----
#pragma unroll
    for (int i = 0; i < I_SZ; ++i) {
        float s = fw[i][0].x + fw[i][0].y + fw[i][0].z + fw[i][0].w
                + fw[i][1].x + fw[i][1].y + fw[i][1].z + fw[i][1].w;
        s += __shfl_xor(s, 1); s += __shfl_xor(s, 2);
        s += __shfl_xor(s, 4); s += __shfl_xor(s, 8);
        if (sub == 0) s_sh[j][i] = s;
#pragma unroll
        for (int i2 = i; i2 < I_SZ; ++i2) {
            float g = fw[i][0].x * fw[i2][0].x + fw[i][0].y * fw[i2][0].y
                    + fw[i][0].z * fw[i2][0].z + fw[i][0].w * fw[i2][0].w
                    + fw[i][1].x * fw[i2][1].x + fw[i][1].y * fw[i2][1].y
                    + fw[i][1].z * fw[i2][1].z + fw[i][1].w * fw[i2][1].w;
            g += __shfl_xor(g, 1); g += __shfl_xor(g, 2);
            g += __shfl_xor(g, 4); g += __shfl_xor(g, 8);
            if (sub == 0) { G_sh[j][i * 7 + i2] = g; G_sh[j][i2 * 7 + i] = g; }
        }
    }
    __syncthreads();

    // ---- Phase 2: 10 iterations on the 7x7 system ----
    for (int t = 0; t < ITERS; ++t) {
        if (tid < I_SZ * 64) {                 // waves 0..6
            const int ii = tid >> 6;
            const int jj = tid & 63;
            float l;
            if (t == 0) {
                l = s_sh[jj][ii];              // c0 = ones
            } else {
                const int rb = t & 1;
                l = 0.f;
#pragma unroll
                for (int i2 = 0; i2 < I_SZ; ++i2)
                    l = fmaf(w_sh[rb][jj][i2], G_sh[jj][ii * 7 + i2], l);
            }
            float mx = l;
#pragma unroll
            for (int off = 32; off > 0; off >>= 1)
                mx = fmaxf(mx, __shfl_xor(mx, off));
            float ex = __expf(l - mx);
            float sm = ex;
#pragma unroll
            for (int off = 32; off > 0; off >>= 1)
                sm += __shfl_xor(sm, off);
            float r = ex / sm;
            if (t == ITERS - 1)
                r_out[(size_t)b * (I_SZ * J_SZ) + ii * 64 + jj] = r;
            w_sh[(t + 1) & 1][jj][ii] = p_sh[ii] * r;
        }
        __syncthreads();
    }

    // ---- Phase 3: c from registers ----
    float4 a0 = make_float4(0.f, 0.f, 0.f, 0.f);
    float4 a1 = make_float4(0.f, 0.f, 0.f, 0.f);
#pragma unroll
    for (int i = 0; i < I_SZ; ++i) {
        float wv = w_sh[ITERS & 1][j][i];
        a0.x = fmaf(wv, fw[i][0].x, a0.x); a0.y = fmaf(wv, fw[i][0].y, a0.y);
        a0.z = fmaf(wv, fw[i][0].z, a0.z); a0.w = fmaf(wv, fw[i][0].w, a0.w);
        a1.x = fmaf(wv, fw[i][1].x, a1.x); a1.y = fmaf(wv, fw[i][1].y, a1.y);
        a1.z = fmaf(wv, fw[i][1].z, a1.z); a1.w = fmaf(wv, fw[i][1].w, a1.w);
    }
    float* dst = c_out + (size_t)b * N_SZ + j * E_SZ + sub * 8;
    *(float4*)(dst)     = a0;
    *(float4*)(dst + 4) = a1;
}

extern "C" void kernel_launch(void* const* d_in, const int* in_sizes, int n_in,
                              void* d_out, int out_size, void* d_ws, size_t ws_size,
                              hipStream_t stream) {
    const float* f = (const float*)d_in[0];   // [512,7,512]
    const float* p = (const float*)d_in[1];   // [512,7]
    const float* W = (const float*)d_in[2];   // [7,512,64,128]
    float* out = (float*)d_out;               // c (512*64*128) then r (512*7*64)
    float* fW  = (float*)d_ws;                // 117.4 MB scratch

    vote_gemm_mfma<<<dim3(N_SZ / 128, B_SZ / 128, I_SZ), 256, 0, stream>>>(f, W, fW);
    routing_kernel<<<B_SZ, 1024, 0, stream>>>(fW, p, out, out + (size_t)B_SZ * N_SZ);
}

// Round 5
// 288.545 us; speedup vs baseline: 2.2815x; 1.2076x over previous
//
#include <hip/hip_runtime.h>
#include <hip/hip_bf16.h>

#define B_SZ 512
#define I_SZ 7
#define D_SZ 512
#define J_SZ 64
#define E_SZ 128
#define N_SZ 8192
#define ITERS 10

typedef __attribute__((ext_vector_type(8))) short bf16x8;
typedef __attribute__((ext_vector_type(4))) float f32x4;

#define AST 40   // LDS row stride in bf16 shorts (32 k + 8 pad), 16B-aligned rows
#define BST 40

#if defined(__has_builtin)
#if __has_builtin(__builtin_amdgcn_cvt_pk_bf16_f32)
#define HAVE_CVT_PK_BF16 1
#endif
#endif

// Split a PAIR of fp32 into packed-bf16 hi and lo words (RNE both stages).
// hp low short = bf16(x0), high short = bf16(x1); same for lp with residuals.
// ~3 VALU ops/value on gfx950 (v_cvt_pk_bf16_f32), ~7/value fallback.
__device__ inline void split2(float x0, float x1, unsigned& hp, unsigned& lp) {
#ifdef HAVE_CVT_PK_BF16
    auto h = __builtin_amdgcn_cvt_pk_bf16_f32(x0, x1);
    hp = __builtin_bit_cast(unsigned, h);
    union { unsigned u; float f; } b0, b1;
    b0.u = hp << 16;
    b1.u = hp & 0xFFFF0000u;
    auto l = __builtin_amdgcn_cvt_pk_bf16_f32(x0 - b0.f, x1 - b1.f);
    lp = __builtin_bit_cast(unsigned, l);
#else
    union { float f; unsigned u; } u0, u1;
    u0.f = x0; u1.f = x1;
    unsigned r0 = u0.u + 0x7FFF + ((u0.u >> 16) & 1);
    unsigned r1 = u1.u + 0x7FFF + ((u1.u >> 16) & 1);
    hp = __builtin_amdgcn_perm(r1, r0, 0x07060302);   // [r1.hi16 | r0.hi16]
    union { unsigned u; float f; } h0, h1;
    h0.u = r0 & 0xFFFF0000u;
    h1.u = r1 & 0xFFFF0000u;
    union { float f; unsigned u; } s0, s1;
    s0.f = x0 - h0.f; s1.f = x1 - h1.f;
    unsigned q0 = s0.u + 0x7FFF + ((s0.u >> 16) & 1);
    unsigned q1 = s1.u + 0x7FFF + ((s1.u >> 16) & 1);
    lp = __builtin_amdgcn_perm(q1, q0, 0x07060302);
#endif
}

// ---------------------------------------------------------------------------
// Kernel 1: vote GEMM via bf16 MFMA, 3-pass hi/lo split (fp32-grade accuracy).
// fW[b,i,j,e] = sum_d f[b,i,d]*W[i,d,j,e].  Per i: C[512,8192]=A[512,512]*B.
// 128x128 tile, BK=32, 256 threads (4 waves, each 64x64 = 4x4 MFMA tiles).
// acc += Ahi*Bhi + Ahi*Blo + Alo*Bhi  (lo*lo dropped: ~2^-18 rel).
// R5: packed pair-split (v_cvt_pk_bf16_f32 / v_perm fallback) + k-tile
// register prefetch so global latency hides under the MFMA phase.
// ---------------------------------------------------------------------------
__global__ __launch_bounds__(256) void vote_gemm_mfma(
    const float* __restrict__ f,   // [B, I, D]
    const float* __restrict__ W,   // [I, D, N]
    float* __restrict__ fW)        // [B, I, N]
{
    const int i  = blockIdx.z;
    const int m0 = blockIdx.y * 128;
    const int n0 = blockIdx.x * 128;
    const int th = threadIdx.x;

    __shared__ short As_hi[128 * AST], As_lo[128 * AST];  // [m][k]
    __shared__ short Bs_hi[128 * BST], Bs_lo[128 * BST];  // [n][k] (transposed)

    // A staging map: thread -> (row m, k-half of 16)
    const int am  = th >> 1;          // 0..127
    const int akg = th & 1;           // k offset 16*akg
    // B staging map: thread -> (col n, k-half); lanes span n (coalesced rows)
    const int bn  = th & 127;         // 0..127
    const int bkh = th >> 7;          // 0/1

    const float* fA = f + (size_t)(m0 + am) * (I_SZ * D_SZ) + (size_t)i * D_SZ + akg * 16;
    const float* WB = W + (size_t)i * D_SZ * N_SZ + n0 + bn;

    const int wave = th >> 6, lane = th & 63;
    const int wr = wave >> 1, wc = wave & 1;   // wave -> 64x64 quadrant
    const int lm = lane & 15, quad = lane >> 4;

    f32x4 acc[4][4];
#pragma unroll
    for (int a = 0; a < 4; ++a)
#pragma unroll
        for (int c = 0; c < 4; ++c)
            acc[a][c] = (f32x4){0.f, 0.f, 0.f, 0.f};

    // ---- prefetch first k-tile ----
    float av[16], bv[16];
    {
        float4 t0 = *(const float4*)(fA);
        float4 t1 = *(const float4*)(fA + 4);
        float4 t2 = *(const float4*)(fA + 8);
        float4 t3 = *(const float4*)(fA + 12);
        av[0]=t0.x; av[1]=t0.y; av[2]=t0.z; av[3]=t0.w;
        av[4]=t1.x; av[5]=t1.y; av[6]=t1.z; av[7]=t1.w;
        av[8]=t2.x; av[9]=t2.y; av[10]=t2.z; av[11]=t2.w;
        av[12]=t3.x; av[13]=t3.y; av[14]=t3.z; av[15]=t3.w;
        const float* pb = WB + (size_t)(bkh * 16) * N_SZ;
#pragma unroll
        for (int r = 0; r < 16; ++r) bv[r] = pb[(size_t)r * N_SZ];
    }

    for (int k0 = 0; k0 < D_SZ; k0 += 32) {
        // ---- pair-split into packed hi/lo words ----
        uint4 ah0, al0, ah1, al1, bh0, bl0, bh1, bl1;
        split2(av[0],  av[1],  ah0.x, al0.x);
        split2(av[2],  av[3],  ah0.y, al0.y);
        split2(av[4],  av[5],  ah0.z, al0.z);
        split2(av[6],  av[7],  ah0.w, al0.w);
        split2(av[8],  av[9],  ah1.x, al1.x);
        split2(av[10], av[11], ah1.y, al1.y);
        split2(av[12], av[13], ah1.z, al1.z);
        split2(av[14], av[15], ah1.w, al1.w);
        split2(bv[0],  bv[1],  bh0.x, bl0.x);
        split2(bv[2],  bv[3],  bh0.y, bl0.y);
        split2(bv[4],  bv[5],  bh0.z, bl0.z);
        split2(bv[6],  bv[7],  bh0.w, bl0.w);
        split2(bv[8],  bv[9],  bh1.x, bl1.x);
        split2(bv[10], bv[11], bh1.y, bl1.y);
        split2(bv[12], bv[13], bh1.z, bl1.z);
        split2(bv[14], bv[15], bh1.w, bl1.w);

        __syncthreads();   // previous tile's frag reads complete
        *(uint4*)&As_hi[am * AST + akg * 16]     = ah0;
        *(uint4*)&As_hi[am * AST + akg * 16 + 8] = ah1;
        *(uint4*)&As_lo[am * AST + akg * 16]     = al0;
        *(uint4*)&As_lo[am * AST + akg * 16 + 8] = al1;
        *(uint4*)&Bs_hi[bn * BST + bkh * 16]     = bh0;
        *(uint4*)&Bs_hi[bn * BST + bkh * 16 + 8] = bh1;
        *(uint4*)&Bs_lo[bn * BST + bkh * 16]     = bl0;
        *(uint4*)&Bs_lo[bn * BST + bkh * 16 + 8] = bl1;
        __syncthreads();   // staging visible

        // ---- prefetch next k-tile (latency hides under MFMA below) ----
        if (k0 + 32 < D_SZ) {
            const float* pa = fA + k0 + 32;
            float4 t0 = *(const float4*)(pa);
            float4 t1 = *(const float4*)(pa + 4);
            float4 t2 = *(const float4*)(pa + 8);
            float4 t3 = *(const float4*)(pa + 12);
            av[0]=t0.x; av[1]=t0.y; av[2]=t0.z; av[3]=t0.w;
            av[4]=t1.x; av[5]=t1.y; av[6]=t1.z; av[7]=t1.w;
            av[8]=t2.x; av[9]=t2.y; av[10]=t2.z; av[11]=t2.w;
            av[12]=t3.x; av[13]=t3.y; av[14]=t3.z; av[15]=t3.w;
            const float* pb = WB + (size_t)(k0 + 32 + bkh * 16) * N_SZ;
#pragma unroll
            for (int r = 0; r < 16; ++r) bv[r] = pb[(size_t)r * N_SZ];
        }

        // ---- fragment loads + MFMA ----
        bf16x8 Ah[4], Al[4], Bh[4], Bl[4];
#pragma unroll
        for (int t = 0; t < 4; ++t) {
            const int ar = (wr * 64 + t * 16 + lm) * AST + quad * 8;
            Ah[t] = *(const bf16x8*)&As_hi[ar];
            Al[t] = *(const bf16x8*)&As_lo[ar];
            const int br = (wc * 64 + t * 16 + lm) * BST + quad * 8;
            Bh[t] = *(const bf16x8*)&Bs_hi[br];
            Bl[t] = *(const bf16x8*)&Bs_lo[br];
        }
#pragma unroll
        for (int tm = 0; tm < 4; ++tm)
#pragma unroll
            for (int tn = 0; tn < 4; ++tn) {
                acc[tm][tn] = __builtin_amdgcn_mfma_f32_16x16x32_bf16(Ah[tm], Bh[tn], acc[tm][tn], 0, 0, 0);
                acc[tm][tn] = __builtin_amdgcn_mfma_f32_16x16x32_bf16(Ah[tm], Bl[tn], acc[tm][tn], 0, 0, 0);
                acc[tm][tn] = __builtin_amdgcn_mfma_f32_16x16x32_bf16(Al[tm], Bh[tn], acc[tm][tn], 0, 0, 0);
            }
    }

    // ---- write C: D layout col=lane&15, row=quad*4+reg ----
#pragma unroll
    for (int tm = 0; tm < 4; ++tm) {
        const int rowb = m0 + wr * 64 + tm * 16 + quad * 4;
#pragma unroll
        for (int tn = 0; tn < 4; ++tn) {
            const int col = n0 + wc * 64 + tn * 16 + lm;
#pragma unroll
            for (int r = 0; r < 4; ++r)
                fW[((size_t)(rowb + r) * I_SZ + i) * N_SZ + col] = acc[tm][tn][r];
        }
    }
}

// ---------------------------------------------------------------------------
// Kernel 2: routing via Gram matrices (unchanged from R4 — ~25 us, near floor).
// 1024 threads per block, one block per b. Thread (j=tid>>4, sub=tid&15)
// holds fW[b,:,j,sub*8..+8) in 56 VGPRs (no spill at the 128-reg cap).
// ---------------------------------------------------------------------------
__global__ __launch_bounds__(1024) void routing_kernel(
    const float* __restrict__ fW,  // [B, I, N]
    const float* __restrict__ p,   // [B, I]
    float* __restrict__ c_out,     // [B, J, E]
    float* __restrict__ r_out)     // [B, I, J]
{
    const int b   = blockIdx.x;
    const int tid = threadIdx.x;
    const int j   = tid >> 4;      // 0..63
    const int sub = tid & 15;      // e-chunk [sub*8, sub*8+8)

    __shared__ float G_sh[64][49];
    __shared__ float s_sh[64][9];
    __shared__ float w_sh[2][64][9];
    __shared__ float p_sh[8];

    if (tid < I_SZ) p_sh[tid] = p[(size_t)b * I_SZ + tid];

    float4 fw[I_SZ][2];
    const float* base = fW + (size_t)b * I_SZ * N_SZ + j * E_SZ + sub * 8;
#pragma unroll
    for (int i = 0; i < I_SZ; ++i) {
        fw[i][0] = *(const float4*)(base + (size_t)i * N_SZ);
        fw[i][1] = *(const float4*)(base + (size_t)i * N_SZ + 4);
    }

    // ---- Phase 1: Gram + row sums (reduce over 16 sub-lanes) ----
#pragma unroll
    for (int i = 0; i < I_SZ; ++i) {
        float s = fw[i][0].x + fw[i][0].y + fw[i][0].z + fw[i][0].w
                + fw[i][1].x + fw[i][1].y + fw[i][1].z + fw[i][1].w;
        s += __shfl_xor(s, 1); s += __shfl_xor(s, 2);
        s += __shfl_xor(s, 4); s += __shfl_xor(s, 8);
        if (sub == 0) s_sh[j][i] = s;
#pragma unroll
        for (int i2 = i; i2 < I_SZ; ++i2) {
            float g = fw[i][0].x * fw[i2][0].x + fw[i][0].y * fw[i2][0].y
                    + fw[i][0].z * fw[i2][0].z + fw[i][0].w * fw[i2][0].w
                    + fw[i][1].x * fw[i2][1].x + fw[i][1].y * fw[i2][1].y
                    + fw[i][1].z * fw[i2][1].z + fw[i][1].w * fw[i2][1].w;
            g += __shfl_xor(g, 1); g += __shfl_xor(g, 2);
            g += __shfl_xor(g, 4); g += __shfl_xor(g, 8);
            if (sub == 0) { G_sh[j][i * 7 + i2] = g; G_sh[j][i2 * 7 + i] = g; }
        }
    }
    __syncthreads();

    // ---- Phase 2: 10 iterations on the 7x7 system ----
    for (int t = 0; t < ITERS; ++t) {
        if (tid < I_SZ * 64) {                 // waves 0..6
            const int ii = tid >> 6;
            const int jj = tid & 63;
            float l;
            if (t == 0) {
                l = s_sh[jj][ii];              // c0 = ones
            } else {
                const int rb = t & 1;
                l = 0.f;
#pragma unroll
                for (int i2 = 0; i2 < I_SZ; ++i2)
                    l = fmaf(w_sh[rb][jj][i2], G_sh[jj][ii * 7 + i2], l);
            }
            float mx = l;
#pragma unroll
            for (int off = 32; off > 0; off >>= 1)
                mx = fmaxf(mx, __shfl_xor(mx, off));
            float ex = __expf(l - mx);
            float sm = ex;
#pragma unroll
            for (int off = 32; off > 0; off >>= 1)
                sm += __shfl_xor(sm, off);
            float r = ex / sm;
            if (t == ITERS - 1)
                r_out[(size_t)b * (I_SZ * J_SZ) + ii * 64 + jj] = r;
            w_sh[(t + 1) & 1][jj][ii] = p_sh[ii] * r;
        }
        __syncthreads();
    }

    // ---- Phase 3: c from registers ----
    float4 a0 = make_float4(0.f, 0.f, 0.f, 0.f);
    float4 a1 = make_float4(0.f, 0.f, 0.f, 0.f);
#pragma unroll
    for (int i = 0; i < I_SZ; ++i) {
        float wv = w_sh[ITERS & 1][j][i];
        a0.x = fmaf(wv, fw[i][0].x, a0.x); a0.y = fmaf(wv, fw[i][0].y, a0.y);
        a0.z = fmaf(wv, fw[i][0].z, a0.z); a0.w = fmaf(wv, fw[i][0].w, a0.w);
        a1.x = fmaf(wv, fw[i][1].x, a1.x); a1.y = fmaf(wv, fw[i][1].y, a1.y);
        a1.z = fmaf(wv, fw[i][1].z, a1.z); a1.w = fmaf(wv, fw[i][1].w, a1.w);
    }
    float* dst = c_out + (size_t)b * N_SZ + j * E_SZ + sub * 8;
    *(float4*)(dst)     = a0;
    *(float4*)(dst + 4) = a1;
}

extern "C" void kernel_launch(void* const* d_in, const int* in_sizes, int n_in,
                              void* d_out, int out_size, void* d_ws, size_t ws_size,
                              hipStream_t stream) {
    const float* f = (const float*)d_in[0];   // [512,7,512]
    const float* p = (const float*)d_in[1];   // [512,7]
    const float* W = (const float*)d_in[2];   // [7,512,64,128]
    float* out = (float*)d_out;               // c (512*64*128) then r (512*7*64)
    float* fW  = (float*)d_ws;                // 117.4 MB scratch

    vote_gemm_mfma<<<dim3(N_SZ / 128, B_SZ / 128, I_SZ), 256, 0, stream>>>(f, W, fW);
    routing_kernel<<<B_SZ, 1024, 0, stream>>>(fW, p, out, out + (size_t)B_SZ * N_SZ);
}